// Round 13
// baseline (143.951 us; speedup 1.0000x reference)
//
#include <hip/hip_runtime.h>
#include <math.h>

#define CIN    384
#define NPIX   3136      // 56*56

typedef float vf4 __attribute__((ext_vector_type(4)));
typedef __attribute__((ext_vector_type(4))) float f32x4;
typedef __attribute__((ext_vector_type(8))) short bf16x8;
typedef __attribute__((ext_vector_type(8))) unsigned short u16x8;

__device__ __forceinline__ unsigned short f2bf(float f) {
    unsigned u = __float_as_uint(f);
    u = (u + 0x7FFF + ((u >> 16) & 1)) >> 16;
    return (unsigned short)u;
}
__device__ __forceinline__ float bf2f(unsigned short h) {
    return __uint_as_float(((unsigned)h) << 16);
}

// ---------------------------------------------------------------------------
// k_front (MEASUREMENT: grid 3x28800/3=3 passes; blk%9600 selects work; all
// passes write byte-identical values -> benign races, deterministic output)
//   [0,6144) pool x -> Xhi/Xlo bf16 transposed [p=848][k=384]
//   [6144,9024) split proj_w ; [9024,9600) split proj2_w
// ---------------------------------------------------------------------------
__global__ __launch_bounds__(256) void k_front(const float* __restrict__ x,
                                               const float* __restrict__ W1,
                                               const float* __restrict__ W2,
                                               unsigned short* __restrict__ Xhi,
                                               unsigned short* __restrict__ Xlo,
                                               unsigned short* __restrict__ Whi1,
                                               unsigned short* __restrict__ Wlo1,
                                               unsigned short* __restrict__ Whi2,
                                               unsigned short* __restrict__ Wlo2) {
    int blk = blockIdx.x % 9600;   // 3 identical passes
    int t = threadIdx.x;
    if (blk >= 9024) {           // W2 split
        int i = (blk - 9024) * 256 + t;
        float w = W2[i];
        unsigned short hi = f2bf(w);
        Whi2[i] = hi;
        Wlo2[i] = f2bf(w - bf2f(hi));
        return;
    }
    if (blk >= 6144) {           // W1 split
        int i = (blk - 6144) * 256 + t;
        float w = W1[i];
        unsigned short hi = f2bf(w);
        Whi1[i] = hi;
        Wlo1[i] = f2bf(w - bf2f(hi));
        return;
    }
    int Bi = blk / CIN;
    int ch = blk - Bi * CIN;
    __shared__ float ps[56][14];
    __shared__ float s14[14][14];
    const float* xp = x + (size_t)(Bi * CIN + ch) * NPIX;
    for (int p = t; p < 784; p += 256) {
        int row = p / 14, cb = p % 14;
        const vf4 v = __builtin_nontemporal_load(
            reinterpret_cast<const vf4*>(xp + row * 56 + cb * 4));
        ps[row][cb] = v.x + v.y + v.z + v.w;
    }
    __syncthreads();
    if (t < 196) {
        int ri = t / 14, cb = t % 14;
        s14[ri][cb] = ps[4*ri][cb] + ps[4*ri+1][cb] + ps[4*ri+2][cb] + ps[4*ri+3][cb];
    }
    __syncthreads();
    if (t < 49) {
        int i = t / 7, j = t % 7;
        float s = (s14[2*i][2*j] + s14[2*i][2*j+1] + s14[2*i+1][2*j] + s14[2*i+1][2*j+1])
                  * (1.0f / 64.0f);
        int p = Bi * 49 + t;
        unsigned short hi = f2bf(s);
        Xhi[(size_t)p * 384 + ch] = hi;
        Xlo[(size_t)p * 384 + ch] = f2bf(s - bf2f(hi));
    } else if (t >= 64 && t < 68) {
        int m = t - 64;
        int mi = m / 2, mj = m % 2;
        float s = 0.f;
        for (int ri = 7*mi; ri < 7*mi + 7; ++ri)
            for (int cb = 7*mj; cb < 7*mj + 7; ++cb)
                s += s14[ri][cb];
        s *= (1.0f / 784.0f);
        int p = 784 + Bi * 4 + m;
        unsigned short hi = f2bf(s);
        Xhi[(size_t)p * 384 + ch] = hi;
        Xlo[(size_t)p * 384 + ch] = f2bf(s - bf2f(hi));
    }
}

// ---------------------------------------------------------------------------
// k_fuse: per-(Bi,head): y = W1@x+b (240x53, bf16x3 MFMA, y in LDS),
//         attention with wave-parallel reductions; osT bf16 hi/lo [Bi][64][384]
// ---------------------------------------------------------------------------
__global__ __launch_bounds__(512) void k_fuse(
        const unsigned short* __restrict__ Whi, const unsigned short* __restrict__ Wlo,
        const unsigned short* __restrict__ Xhi, const unsigned short* __restrict__ Xlo,
        const float* __restrict__ proj_b,
        const float* __restrict__ alpha, const float* __restrict__ beta,
        unsigned short* __restrict__ osThi, unsigned short* __restrict__ osTlo) {
    int bb = blockIdx.x;           // 128
    int Bi = bb >> 3, head = bb & 7;
    __shared__ float yT[16560];    // yT[240][69] fp32; staging aliased
    __shared__ float e0[4][49], memb[4][49];
    __shared__ float msum[4];
    __shared__ float agg[8][48];
    __shared__ float anorm[8], pnorm[49];
    __shared__ float simL[8][49];
    __shared__ float assignW[8][49];
    unsigned short* sAh = (unsigned short*)yT;   // 240*40
    unsigned short* sAl = sAh + 9600;
    unsigned short* sBh = sAl + 9600;            // 64*40
    unsigned short* sBl = sBh + 2560;
    int t = threadIdx.x;
    int lane = t & 63, w = t >> 6;
    int fr = lane & 15, fq = lane >> 4;

    int row0 = t >> 2, ko0 = (t & 3) * 8;
    int g0 = row0 / 48, cc0 = row0 - g0 * 48;
    size_t aoff0 = (size_t)(g0 * 384 + head * 48 + cc0) * 384 + ko0;
    int c1 = t + 512;
    int row1 = c1 >> 2, ko1 = (c1 & 3) * 8;
    int g1 = row1 / 48, cc1 = row1 - g1 * 48;
    size_t aoff1 = (size_t)(g1 * 384 + head * 48 + cc1) * 384 + ko1;  // t<448
    int bko = (t & 3) * 8;
    int brow = t >> 2;
    int bp = brow < 49 ? Bi * 49 + brow : 784 + Bi * 4 + (brow - 49);
    size_t boff = (size_t)bp * 384 + bko;                              // t<212

    u16x8 rAh0, rAl0, rAh1, rAl1, rBh, rBl;
    rAh0 = *(const u16x8*)(Whi + aoff0);
    rAl0 = *(const u16x8*)(Wlo + aoff0);
    if (t < 448) { rAh1 = *(const u16x8*)(Whi + aoff1); rAl1 = *(const u16x8*)(Wlo + aoff1); }
    if (t < 212) { rBh  = *(const u16x8*)(Xhi + boff);  rBl  = *(const u16x8*)(Xlo + boff); }

    f32x4 acc[2][4] = {};
    for (int step = 0; step < 12; ++step) {
        *(u16x8*)&sAh[row0 * 40 + ko0] = rAh0;
        *(u16x8*)&sAl[row0 * 40 + ko0] = rAl0;
        if (t < 448) {
            *(u16x8*)&sAh[row1 * 40 + ko1] = rAh1;
            *(u16x8*)&sAl[row1 * 40 + ko1] = rAl1;
        }
        if (t < 212) {
            *(u16x8*)&sBh[brow * 40 + bko] = rBh;
            *(u16x8*)&sBl[brow * 40 + bko] = rBl;
        }
        __syncthreads();
        if (step < 11) {
            int k0 = (step + 1) * 32;
            rAh0 = *(const u16x8*)(Whi + aoff0 + k0);
            rAl0 = *(const u16x8*)(Wlo + aoff0 + k0);
            if (t < 448) { rAh1 = *(const u16x8*)(Whi + aoff1 + k0); rAl1 = *(const u16x8*)(Wlo + aoff1 + k0); }
            if (t < 212) { rBh  = *(const u16x8*)(Xhi + boff + k0);  rBl  = *(const u16x8*)(Xlo + boff + k0); }
        }
        bf16x8 bh[4], bl[4];
#pragma unroll
        for (int nt = 0; nt < 4; ++nt) {
            int r = nt * 16 + fr;
            bh[nt] = *(const bf16x8*)&sBh[r * 40 + fq * 8];
            bl[nt] = *(const bf16x8*)&sBl[r * 40 + fq * 8];
        }
#pragma unroll
        for (int mi = 0; mi < 2; ++mi) {
            int mt = 2 * w + mi;
            if (mt < 15) {
                int r = mt * 16 + fr;
                bf16x8 ah = *(const bf16x8*)&sAh[r * 40 + fq * 8];
                bf16x8 al = *(const bf16x8*)&sAl[r * 40 + fq * 8];
#pragma unroll
                for (int nt = 0; nt < 4; ++nt) {
                    acc[mi][nt] = __builtin_amdgcn_mfma_f32_16x16x32_bf16(ah, bh[nt], acc[mi][nt], 0, 0, 0);
                    acc[mi][nt] = __builtin_amdgcn_mfma_f32_16x16x32_bf16(ah, bl[nt], acc[mi][nt], 0, 0, 0);
                    acc[mi][nt] = __builtin_amdgcn_mfma_f32_16x16x32_bf16(al, bh[nt], acc[mi][nt], 0, 0, 0);
                }
            }
        }
        __syncthreads();
    }
#pragma unroll
    for (int mi = 0; mi < 2; ++mi) {
        int mt = 2 * w + mi;
        if (mt < 15) {
#pragma unroll
            for (int j = 0; j < 4; ++j) {
                int m = mt * 16 + fq * 4 + j;
                int g = m / 48, cc = m - g * 48;
                float bb = proj_b[g * 384 + head * 48 + cc];
#pragma unroll
                for (int nt = 0; nt < 4; ++nt)
                    yT[m * 69 + nt * 16 + fr] = acc[mi][nt][j] + bb;
            }
        }
    }
    __syncthreads();

    // ---- attention (rows: p|k0|v0|k1|v1 x48; cols: 49 agents, +4 clusters)
    const float scale = 0.14433756729740643f;  // 1/sqrt(48)
    if (t < 392) {
        int i = t / 196, r = t % 196;
        int m = r / 49, n = r % 49;
        int rbase = 48 + 96 * i;
        float s = 0.f;
        for (int cc = 0; cc < 48; ++cc)
            s += yT[(rbase + cc) * 69 + 49 + m] * yT[(rbase + cc) * 69 + n];
        s *= scale;
        if (i == 0) e0[m][n] = s; else memb[m][n] = s;
    }
    __syncthreads();
    if (w < 4) {
        float v = (lane < 49) ? e0[w][lane] : -1e30f;
        float mx = v;
#pragma unroll
        for (int off = 32; off; off >>= 1) mx = fmaxf(mx, __shfl_xor(mx, off));
        float e = (lane < 49) ? __expf(v - mx) : 0.f;
        float s = e;
#pragma unroll
        for (int off = 32; off; off >>= 1) s += __shfl_xor(s, off);
        if (lane < 49) e0[w][lane] = e / s;
    } else if (w == 4 && lane < 49) {
        int n = lane;
        float a0 = memb[0][n], a1 = memb[1][n], a2 = memb[2][n], a3 = memb[3][n];
        float mx = fmaxf(fmaxf(a0, a1), fmaxf(a2, a3));
        float x0 = __expf(a0 - mx), x1 = __expf(a1 - mx);
        float x2 = __expf(a2 - mx), x3 = __expf(a3 - mx);
        float s = x0 + x1 + x2 + x3;
        memb[0][n] = x0 / s; memb[1][n] = x1 / s; memb[2][n] = x2 / s; memb[3][n] = x3 / s;
    }
    __syncthreads();
    if (w >= 4) {
        int m = w - 4;
        float v = (lane < 49) ? memb[m][lane] : 0.f;
#pragma unroll
        for (int off = 32; off; off >>= 1) v += __shfl_xor(v, off);
        if (lane == 0) msum[m] = v;
    }
    __syncthreads();
    if (t < 384) {
        int row = t / 48, cc = t % 48;
        float a = 0.f;
        if (row < 4) {
            const float* vr = &yT[(96 + cc) * 69];
            for (int n = 0; n < 49; ++n) a += e0[row][n] * vr[n];
            agg[row][cc] = a + vr[49 + row];
        } else {
            int m = row - 4;
            const float* vr = &yT[(192 + cc) * 69];
            for (int n = 0; n < 49; ++n) a += memb[m][n] * vr[n];
            agg[row][cc] = a / (msum[m] + 1e-6f) + vr[49 + m];
        }
    }
    __syncthreads();
    {
        float v = 0.f;
        if (lane < 48) { float a = agg[w][lane]; v = a * a; }
#pragma unroll
        for (int off = 32; off; off >>= 1) v += __shfl_xor(v, off);
        if (lane == 0) anorm[w] = sqrtf(v) + 1e-6f;
    }
    if (t < 49) {
        int n = t; float s = 0.f;
        for (int cc = 0; cc < 48; ++cc) { float a = yT[cc * 69 + n]; s += a * a; }
        pnorm[n] = sqrtf(s) + 1e-6f;
    }
    __syncthreads();
    if (t < 392) {
        int m = t / 49, n = t - m * 49;
        float dot = 0.f;
        for (int cc = 0; cc < 48; ++cc) dot += agg[m][cc] * yT[cc * 69 + n];
        simL[m][n] = alpha[m] * (dot / (anorm[m] * pnorm[n])) + beta[m];
    }
    __syncthreads();
    if (t < 49) {
        int n = t;
        float mx = -1e30f, e[8];
        for (int m = 0; m < 8; ++m) mx = fmaxf(mx, simL[m][n]);
        float ssum = 0.f;
        for (int m = 0; m < 8; ++m) { e[m] = __expf(simL[m][n] - mx); ssum += e[m]; }
        float inv = 1.f / ssum;
        for (int m = 0; m < 8; ++m) assignW[m][n] = e[m] * inv;
    }
    __syncthreads();
    for (int idx = t; idx < 3072; idx += 512) {
        int n = idx / 48, cc = idx - n * 48;
        float s = 0.f;
        if (n < 49)
            for (int m = 0; m < 8; ++m) s += agg[m][cc] * assignW[m][n];
        size_t o = ((size_t)(Bi * 64 + n)) * 384 + head * 48 + cc;
        unsigned short hi = f2bf(s);
        osThi[o] = hi;
        osTlo[o] = f2bf(s - bf2f(hi));
    }
}

// ---------------------------------------------------------------------------
// k_tail (MEASUREMENT: grid 3x1536; blk%1536 -> 3 identical passes, benign
// identical writes): z = W2 @ osT via bf16x3 MFMA, then bilinear up.
// ---------------------------------------------------------------------------
__global__ __launch_bounds__(256) void k_tail(
        const unsigned short* __restrict__ Whi2, const unsigned short* __restrict__ Wlo2,
        const unsigned short* __restrict__ osThi, const unsigned short* __restrict__ osTlo,
        const float* __restrict__ b2, float* __restrict__ out) {
    int blk = blockIdx.x % 1536;   // 3 identical passes
    int Bi = blk / 96, cg = blk - Bi * 96;
    int ch0 = cg * 4;
    __shared__ unsigned short sAh[16 * 40], sAl[16 * 40];
    __shared__ unsigned short sBh[64 * 40], sBl[64 * 40];
    __shared__ float zL[4][64];
    __shared__ float tmp[4][56][8];
    int t = threadIdx.x;
    int lane = t & 63, w = t >> 6;
    int fr = lane & 15, fq = lane >> 4;
    for (int idx = t; idx < 480; idx += 256) {
        int r = 4 + idx / 40, c = idx % 40;
        sAh[r * 40 + c] = 0; sAl[r * 40 + c] = 0;
    }
    int brow = t >> 2, bko = (t & 3) * 8;
    size_t boff = ((size_t)(Bi * 64 + brow)) * 384 + bko;
    f32x4 acc = {0, 0, 0, 0};
    for (int k0 = 0; k0 < 384; k0 += 32) {
        if (t < 16) {
            int arow = t >> 2, ako = (t & 3) * 8;
            size_t aoff = (size_t)(ch0 + arow) * 384 + k0 + ako;
            *(u16x8*)&sAh[arow * 40 + ako] = *(const u16x8*)(Whi2 + aoff);
            *(u16x8*)&sAl[arow * 40 + ako] = *(const u16x8*)(Wlo2 + aoff);
        }
        *(u16x8*)&sBh[brow * 40 + bko] = *(const u16x8*)(osThi + boff + k0);
        *(u16x8*)&sBl[brow * 40 + bko] = *(const u16x8*)(osTlo + boff + k0);
        __syncthreads();
        bf16x8 ah = *(const bf16x8*)&sAh[fr * 40 + fq * 8];
        bf16x8 al = *(const bf16x8*)&sAl[fr * 40 + fq * 8];
        int rb = w * 16 + fr;
        bf16x8 bh = *(const bf16x8*)&sBh[rb * 40 + fq * 8];
        bf16x8 bl = *(const bf16x8*)&sBl[rb * 40 + fq * 8];
        acc = __builtin_amdgcn_mfma_f32_16x16x32_bf16(ah, bh, acc, 0, 0, 0);
        acc = __builtin_amdgcn_mfma_f32_16x16x32_bf16(ah, bl, acc, 0, 0, 0);
        acc = __builtin_amdgcn_mfma_f32_16x16x32_bf16(al, bh, acc, 0, 0, 0);
        __syncthreads();
    }
    if (fq == 0) {
#pragma unroll
        for (int j = 0; j < 4; ++j)
            zL[j][w * 16 + fr] = acc[j] + b2[ch0 + j];
    }
    __syncthreads();
    for (int idx = t; idx < 1568; idx += 256) {   // 4ch x 56h x 7iw
        int c = idx / 392, rem = idx - c * 392;
        int h = rem / 7, iw = rem - h * 7;
        float sh = (h - 3.5f) * 0.125f;
        int ih0; float fh;
        if (sh <= 0.f)      { ih0 = 0; fh = 0.f; }
        else if (sh >= 6.f) { ih0 = 6; fh = 0.f; }
        else                { ih0 = (int)sh; fh = sh - (float)ih0; }
        int ih1 = min(ih0 + 1, 6);
        float z0 = zL[c][ih0 * 7 + iw];
        tmp[c][h][iw] = z0 + fh * (zL[c][ih1 * 7 + iw] - z0);
    }
    __syncthreads();
    size_t obase = ((size_t)(Bi * 384 + ch0)) * (size_t)NPIX;
    for (int q = t; q < 3136; q += 256) {         // 4 planes x 784 quads
        int c = q / 784, rem = q - c * 784;
        int h = rem / 14, qw = rem - h * 14;
        const float* tr = &tmp[c][h][0];
        vf4 o4;
#pragma unroll
        for (int j = 0; j < 4; ++j) {
            int ww = qw * 4 + j;
            float sw = (ww - 3.5f) * 0.125f;
            int iw0; float fw;
            if (sw <= 0.f)      { iw0 = 0; fw = 0.f; }
            else if (sw >= 6.f) { iw0 = 6; fw = 0.f; }
            else                { iw0 = (int)sw; fw = sw - (float)iw0; }
            int iw1 = min(iw0 + 1, 6);
            float t0 = tr[iw0];
            o4[j] = t0 + fw * (tr[iw1] - t0);
        }
        __builtin_nontemporal_store(o4,
            reinterpret_cast<vf4*>(out + obase + (size_t)q * 4));
    }
}

// ---------------------------------------------------------------------------
extern "C" void kernel_launch(void* const* d_in, const int* in_sizes, int n_in,
                              void* d_out, int out_size, void* d_ws, size_t ws_size,
                              hipStream_t stream) {
    const float* x      = (const float*)d_in[0];
    const float* proj_w = (const float*)d_in[1];
    const float* proj_b = (const float*)d_in[2];
    const float* alpha  = (const float*)d_in[3];
    const float* beta   = (const float*)d_in[4];
    const float* w2     = (const float*)d_in[5];
    const float* b2     = (const float*)d_in[6];
    float* out = (float*)d_out;
    float* ws  = (float*)d_ws;

    unsigned short* Whi1  = (unsigned short*)(ws);                   // 737,280 u16
    unsigned short* Wlo1  = (unsigned short*)(ws + (size_t)368640);
    unsigned short* Xhi   = (unsigned short*)(ws + (size_t)737280);  // 344,064 u16
    unsigned short* Xlo   = (unsigned short*)(ws + (size_t)909312);
    unsigned short* Whi2  = (unsigned short*)(ws + (size_t)1081344); // 147,456 u16
    unsigned short* Wlo2  = (unsigned short*)(ws + (size_t)1155072);
    unsigned short* osThi = (unsigned short*)(ws + (size_t)1228800); // 393,216 u16
    unsigned short* osTlo = (unsigned short*)(ws + (size_t)1425408);
    // total ws ~6.5 MB

    // MEASUREMENT ROUND 2: k_front and k_tail each run 3 identical passes
    // inside ONE dispatch (grid x3) so their rows exceed the ~45us harness
    // fills and surface in top-5 WITH counters. dur ~= 73 + 2F + 2T.
    k_front<<<dim3(28800), 256, 0, stream>>>(x, proj_w, w2, Xhi, Xlo, Whi1, Wlo1, Whi2, Wlo2);
    k_fuse <<<dim3(128),   512, 0, stream>>>(Whi1, Wlo1, Xhi, Xlo, proj_b, alpha, beta, osThi, osTlo);
    k_tail <<<dim3(4608),  256, 0, stream>>>(Whi2, Wlo2, osThi, osTlo, b2, out);
}

// Round 14
// 71.429 us; speedup vs baseline: 2.0153x; 2.0153x over previous
//
#include <hip/hip_runtime.h>
#include <math.h>

#define CIN    384
#define NPIX   3136      // 56*56

typedef float vf4 __attribute__((ext_vector_type(4)));
typedef __attribute__((ext_vector_type(4))) float f32x4;
typedef __attribute__((ext_vector_type(8))) short bf16x8;
typedef __attribute__((ext_vector_type(8))) unsigned short u16x8;

__device__ __forceinline__ unsigned short f2bf(float f) {
    unsigned u = __float_as_uint(f);
    u = (u + 0x7FFF + ((u >> 16) & 1)) >> 16;
    return (unsigned short)u;
}
__device__ __forceinline__ float bf2f(unsigned short h) {
    return __uint_as_float(((unsigned)h) << 16);
}

// ---------------------------------------------------------------------------
// k_front: [0,6144) pool x -> Xhi/Xlo bf16 transposed [p=848][k=384]
//          [6144,9024) split proj_w ; [9024,9600) split proj2_w
// (measured r13: ~11.8 us ~= 77MB read floor -> at roofline, unchanged)
// ---------------------------------------------------------------------------
__global__ __launch_bounds__(256) void k_front(const float* __restrict__ x,
                                               const float* __restrict__ W1,
                                               const float* __restrict__ W2,
                                               unsigned short* __restrict__ Xhi,
                                               unsigned short* __restrict__ Xlo,
                                               unsigned short* __restrict__ Whi1,
                                               unsigned short* __restrict__ Wlo1,
                                               unsigned short* __restrict__ Whi2,
                                               unsigned short* __restrict__ Wlo2) {
    int blk = blockIdx.x;
    int t = threadIdx.x;
    if (blk >= 9024) {           // W2 split
        int i = (blk - 9024) * 256 + t;
        float w = W2[i];
        unsigned short hi = f2bf(w);
        Whi2[i] = hi;
        Wlo2[i] = f2bf(w - bf2f(hi));
        return;
    }
    if (blk >= 6144) {           // W1 split
        int i = (blk - 6144) * 256 + t;
        float w = W1[i];
        unsigned short hi = f2bf(w);
        Whi1[i] = hi;
        Wlo1[i] = f2bf(w - bf2f(hi));
        return;
    }
    int Bi = blk / CIN;
    int ch = blk - Bi * CIN;
    __shared__ float ps[56][14];
    __shared__ float s14[14][14];
    const float* xp = x + (size_t)(Bi * CIN + ch) * NPIX;
    for (int p = t; p < 784; p += 256) {
        int row = p / 14, cb = p % 14;
        const vf4 v = __builtin_nontemporal_load(
            reinterpret_cast<const vf4*>(xp + row * 56 + cb * 4));
        ps[row][cb] = v.x + v.y + v.z + v.w;
    }
    __syncthreads();
    if (t < 196) {
        int ri = t / 14, cb = t % 14;
        s14[ri][cb] = ps[4*ri][cb] + ps[4*ri+1][cb] + ps[4*ri+2][cb] + ps[4*ri+3][cb];
    }
    __syncthreads();
    if (t < 49) {
        int i = t / 7, j = t % 7;
        float s = (s14[2*i][2*j] + s14[2*i][2*j+1] + s14[2*i+1][2*j] + s14[2*i+1][2*j+1])
                  * (1.0f / 64.0f);
        int p = Bi * 49 + t;
        unsigned short hi = f2bf(s);
        Xhi[(size_t)p * 384 + ch] = hi;
        Xlo[(size_t)p * 384 + ch] = f2bf(s - bf2f(hi));
    } else if (t >= 64 && t < 68) {
        int m = t - 64;
        int mi = m / 2, mj = m % 2;
        float s = 0.f;
        for (int ri = 7*mi; ri < 7*mi + 7; ++ri)
            for (int cb = 7*mj; cb < 7*mj + 7; ++cb)
                s += s14[ri][cb];
        s *= (1.0f / 784.0f);
        int p = 784 + Bi * 4 + m;
        unsigned short hi = f2bf(s);
        Xhi[(size_t)p * 384 + ch] = hi;
        Xlo[(size_t)p * 384 + ch] = f2bf(s - bf2f(hi));
    }
}

// ---------------------------------------------------------------------------
// k_fuse: per-(Bi,head): y = W1@x+b (240x53, bf16x3 MFMA, y in LDS),
//         attention with wave-parallel reductions; osT bf16 hi/lo [Bi][64][384]
// (measured r12: ~19 us; unchanged this round)
// ---------------------------------------------------------------------------
__global__ __launch_bounds__(512) void k_fuse(
        const unsigned short* __restrict__ Whi, const unsigned short* __restrict__ Wlo,
        const unsigned short* __restrict__ Xhi, const unsigned short* __restrict__ Xlo,
        const float* __restrict__ proj_b,
        const float* __restrict__ alpha, const float* __restrict__ beta,
        unsigned short* __restrict__ osThi, unsigned short* __restrict__ osTlo) {
    int bb = blockIdx.x;           // 128
    int Bi = bb >> 3, head = bb & 7;
    __shared__ float yT[16560];    // yT[240][69] fp32; staging aliased
    __shared__ float e0[4][49], memb[4][49];
    __shared__ float msum[4];
    __shared__ float agg[8][48];
    __shared__ float anorm[8], pnorm[49];
    __shared__ float simL[8][49];
    __shared__ float assignW[8][49];
    unsigned short* sAh = (unsigned short*)yT;   // 240*40
    unsigned short* sAl = sAh + 9600;
    unsigned short* sBh = sAl + 9600;            // 64*40
    unsigned short* sBl = sBh + 2560;
    int t = threadIdx.x;
    int lane = t & 63, w = t >> 6;
    int fr = lane & 15, fq = lane >> 4;

    int row0 = t >> 2, ko0 = (t & 3) * 8;
    int g0 = row0 / 48, cc0 = row0 - g0 * 48;
    size_t aoff0 = (size_t)(g0 * 384 + head * 48 + cc0) * 384 + ko0;
    int c1 = t + 512;
    int row1 = c1 >> 2, ko1 = (c1 & 3) * 8;
    int g1 = row1 / 48, cc1 = row1 - g1 * 48;
    size_t aoff1 = (size_t)(g1 * 384 + head * 48 + cc1) * 384 + ko1;  // t<448
    int bko = (t & 3) * 8;
    int brow = t >> 2;
    int bp = brow < 49 ? Bi * 49 + brow : 784 + Bi * 4 + (brow - 49);
    size_t boff = (size_t)bp * 384 + bko;                              // t<212

    u16x8 rAh0, rAl0, rAh1, rAl1, rBh, rBl;
    rAh0 = *(const u16x8*)(Whi + aoff0);
    rAl0 = *(const u16x8*)(Wlo + aoff0);
    if (t < 448) { rAh1 = *(const u16x8*)(Whi + aoff1); rAl1 = *(const u16x8*)(Wlo + aoff1); }
    if (t < 212) { rBh  = *(const u16x8*)(Xhi + boff);  rBl  = *(const u16x8*)(Xlo + boff); }

    f32x4 acc[2][4] = {};
    for (int step = 0; step < 12; ++step) {
        *(u16x8*)&sAh[row0 * 40 + ko0] = rAh0;
        *(u16x8*)&sAl[row0 * 40 + ko0] = rAl0;
        if (t < 448) {
            *(u16x8*)&sAh[row1 * 40 + ko1] = rAh1;
            *(u16x8*)&sAl[row1 * 40 + ko1] = rAl1;
        }
        if (t < 212) {
            *(u16x8*)&sBh[brow * 40 + bko] = rBh;
            *(u16x8*)&sBl[brow * 40 + bko] = rBl;
        }
        __syncthreads();
        if (step < 11) {
            int k0 = (step + 1) * 32;
            rAh0 = *(const u16x8*)(Whi + aoff0 + k0);
            rAl0 = *(const u16x8*)(Wlo + aoff0 + k0);
            if (t < 448) { rAh1 = *(const u16x8*)(Whi + aoff1 + k0); rAl1 = *(const u16x8*)(Wlo + aoff1 + k0); }
            if (t < 212) { rBh  = *(const u16x8*)(Xhi + boff + k0);  rBl  = *(const u16x8*)(Xlo + boff + k0); }
        }
        bf16x8 bh[4], bl[4];
#pragma unroll
        for (int nt = 0; nt < 4; ++nt) {
            int r = nt * 16 + fr;
            bh[nt] = *(const bf16x8*)&sBh[r * 40 + fq * 8];
            bl[nt] = *(const bf16x8*)&sBl[r * 40 + fq * 8];
        }
#pragma unroll
        for (int mi = 0; mi < 2; ++mi) {
            int mt = 2 * w + mi;
            if (mt < 15) {
                int r = mt * 16 + fr;
                bf16x8 ah = *(const bf16x8*)&sAh[r * 40 + fq * 8];
                bf16x8 al = *(const bf16x8*)&sAl[r * 40 + fq * 8];
#pragma unroll
                for (int nt = 0; nt < 4; ++nt) {
                    acc[mi][nt] = __builtin_amdgcn_mfma_f32_16x16x32_bf16(ah, bh[nt], acc[mi][nt], 0, 0, 0);
                    acc[mi][nt] = __builtin_amdgcn_mfma_f32_16x16x32_bf16(ah, bl[nt], acc[mi][nt], 0, 0, 0);
                    acc[mi][nt] = __builtin_amdgcn_mfma_f32_16x16x32_bf16(al, bh[nt], acc[mi][nt], 0, 0, 0);
                }
            }
        }
        __syncthreads();
    }
#pragma unroll
    for (int mi = 0; mi < 2; ++mi) {
        int mt = 2 * w + mi;
        if (mt < 15) {
#pragma unroll
            for (int j = 0; j < 4; ++j) {
                int m = mt * 16 + fq * 4 + j;
                int g = m / 48, cc = m - g * 48;
                float bb = proj_b[g * 384 + head * 48 + cc];
#pragma unroll
                for (int nt = 0; nt < 4; ++nt)
                    yT[m * 69 + nt * 16 + fr] = acc[mi][nt][j] + bb;
            }
        }
    }
    __syncthreads();

    // ---- attention (rows: p|k0|v0|k1|v1 x48; cols: 49 agents, +4 clusters)
    const float scale = 0.14433756729740643f;  // 1/sqrt(48)
    if (t < 392) {
        int i = t / 196, r = t % 196;
        int m = r / 49, n = r % 49;
        int rbase = 48 + 96 * i;
        float s = 0.f;
        for (int cc = 0; cc < 48; ++cc)
            s += yT[(rbase + cc) * 69 + 49 + m] * yT[(rbase + cc) * 69 + n];
        s *= scale;
        if (i == 0) e0[m][n] = s; else memb[m][n] = s;
    }
    __syncthreads();
    if (w < 4) {
        float v = (lane < 49) ? e0[w][lane] : -1e30f;
        float mx = v;
#pragma unroll
        for (int off = 32; off; off >>= 1) mx = fmaxf(mx, __shfl_xor(mx, off));
        float e = (lane < 49) ? __expf(v - mx) : 0.f;
        float s = e;
#pragma unroll
        for (int off = 32; off; off >>= 1) s += __shfl_xor(s, off);
        if (lane < 49) e0[w][lane] = e / s;
    } else if (w == 4 && lane < 49) {
        int n = lane;
        float a0 = memb[0][n], a1 = memb[1][n], a2 = memb[2][n], a3 = memb[3][n];
        float mx = fmaxf(fmaxf(a0, a1), fmaxf(a2, a3));
        float x0 = __expf(a0 - mx), x1 = __expf(a1 - mx);
        float x2 = __expf(a2 - mx), x3 = __expf(a3 - mx);
        float s = x0 + x1 + x2 + x3;
        memb[0][n] = x0 / s; memb[1][n] = x1 / s; memb[2][n] = x2 / s; memb[3][n] = x3 / s;
    }
    __syncthreads();
    if (w >= 4) {
        int m = w - 4;
        float v = (lane < 49) ? memb[m][lane] : 0.f;
#pragma unroll
        for (int off = 32; off; off >>= 1) v += __shfl_xor(v, off);
        if (lane == 0) msum[m] = v;
    }
    __syncthreads();
    if (t < 384) {
        int row = t / 48, cc = t % 48;
        float a = 0.f;
        if (row < 4) {
            const float* vr = &yT[(96 + cc) * 69];
            for (int n = 0; n < 49; ++n) a += e0[row][n] * vr[n];
            agg[row][cc] = a + vr[49 + row];
        } else {
            int m = row - 4;
            const float* vr = &yT[(192 + cc) * 69];
            for (int n = 0; n < 49; ++n) a += memb[m][n] * vr[n];
            agg[row][cc] = a / (msum[m] + 1e-6f) + vr[49 + m];
        }
    }
    __syncthreads();
    {
        float v = 0.f;
        if (lane < 48) { float a = agg[w][lane]; v = a * a; }
#pragma unroll
        for (int off = 32; off; off >>= 1) v += __shfl_xor(v, off);
        if (lane == 0) anorm[w] = sqrtf(v) + 1e-6f;
    }
    if (t < 49) {
        int n = t; float s = 0.f;
        for (int cc = 0; cc < 48; ++cc) { float a = yT[cc * 69 + n]; s += a * a; }
        pnorm[n] = sqrtf(s) + 1e-6f;
    }
    __syncthreads();
    if (t < 392) {
        int m = t / 49, n = t - m * 49;
        float dot = 0.f;
        for (int cc = 0; cc < 48; ++cc) dot += agg[m][cc] * yT[cc * 69 + n];
        simL[m][n] = alpha[m] * (dot / (anorm[m] * pnorm[n])) + beta[m];
    }
    __syncthreads();
    if (t < 49) {
        int n = t;
        float mx = -1e30f, e[8];
        for (int m = 0; m < 8; ++m) mx = fmaxf(mx, simL[m][n]);
        float ssum = 0.f;
        for (int m = 0; m < 8; ++m) { e[m] = __expf(simL[m][n] - mx); ssum += e[m]; }
        float inv = 1.f / ssum;
        for (int m = 0; m < 8; ++m) assignW[m][n] = e[m] * inv;
    }
    __syncthreads();
    for (int idx = t; idx < 3072; idx += 512) {
        int n = idx / 48, cc = idx - n * 48;
        float s = 0.f;
        if (n < 49)
            for (int m = 0; m < 8; ++m) s += agg[m][cc] * assignW[m][n];
        size_t o = ((size_t)(Bi * 64 + n)) * 384 + head * 48 + cc;
        unsigned short hi = f2bf(s);
        osThi[o] = hi;
        osTlo[o] = f2bf(s - bf2f(hi));
    }
}

// ---------------------------------------------------------------------------
// k_tail v2: z = W2 @ osT via bf16x3 MFMA (LDS-staged), then bilinear up with
// TABLE-DRIVEN weights (single 56-entry (i0,f) table shared by h and w paths),
// padded tmp[..][9] (stride 9 coprime 32 -> no bank aliasing).
// ---------------------------------------------------------------------------
__global__ __launch_bounds__(256) void k_tail(
        const unsigned short* __restrict__ Whi2, const unsigned short* __restrict__ Wlo2,
        const unsigned short* __restrict__ osThi, const unsigned short* __restrict__ osTlo,
        const float* __restrict__ b2, float* __restrict__ out) {
    int blk = blockIdx.x;          // 1536 = 16 * 96
    int Bi = blk / 96, cg = blk - Bi * 96;
    int ch0 = cg * 4;
    __shared__ unsigned short sAh[16 * 40], sAl[16 * 40];
    __shared__ unsigned short sBh[64 * 40], sBl[64 * 40];
    __shared__ float zL[4][64];
    __shared__ float tmp[4][56][9];   // stride 9: bank-friendly
    __shared__ float wf[56];          // lerp fraction (0 on clamped rows)
    __shared__ int   wi[56];          // lower source index
    int t = threadIdx.x;
    int lane = t & 63, w = t >> 6;
    int fr = lane & 15, fq = lane >> 4;
    // build the 56-entry source-index/weight table (same map for h and w)
    if (t < 56) {
        float s = (t - 3.5f) * 0.125f;
        int i0; float f;
        if (s <= 0.f)      { i0 = 0; f = 0.f; }
        else if (s >= 6.f) { i0 = 6; f = 0.f; }
        else               { i0 = (int)s; f = s - (float)i0; }
        wi[t] = i0; wf[t] = f;
    }
    for (int idx = t; idx < 480; idx += 256) {   // zero A pad rows 4..15
        int r = 4 + idx / 40, c = idx % 40;
        sAh[r * 40 + c] = 0; sAl[r * 40 + c] = 0;
    }
    int brow = t >> 2, bko = (t & 3) * 8;
    size_t boff = ((size_t)(Bi * 64 + brow)) * 384 + bko;
    f32x4 acc = {0, 0, 0, 0};
    for (int k0 = 0; k0 < 384; k0 += 32) {
        if (t < 16) {
            int arow = t >> 2, ako = (t & 3) * 8;
            size_t aoff = (size_t)(ch0 + arow) * 384 + k0 + ako;
            *(u16x8*)&sAh[arow * 40 + ako] = *(const u16x8*)(Whi2 + aoff);
            *(u16x8*)&sAl[arow * 40 + ako] = *(const u16x8*)(Wlo2 + aoff);
        }
        *(u16x8*)&sBh[brow * 40 + bko] = *(const u16x8*)(osThi + boff + k0);
        *(u16x8*)&sBl[brow * 40 + bko] = *(const u16x8*)(osTlo + boff + k0);
        __syncthreads();
        bf16x8 ah = *(const bf16x8*)&sAh[fr * 40 + fq * 8];
        bf16x8 al = *(const bf16x8*)&sAl[fr * 40 + fq * 8];
        int rb = w * 16 + fr;
        bf16x8 bh = *(const bf16x8*)&sBh[rb * 40 + fq * 8];
        bf16x8 bl = *(const bf16x8*)&sBl[rb * 40 + fq * 8];
        acc = __builtin_amdgcn_mfma_f32_16x16x32_bf16(ah, bh, acc, 0, 0, 0);
        acc = __builtin_amdgcn_mfma_f32_16x16x32_bf16(ah, bl, acc, 0, 0, 0);
        acc = __builtin_amdgcn_mfma_f32_16x16x32_bf16(al, bh, acc, 0, 0, 0);
        __syncthreads();
    }
    if (fq == 0) {
#pragma unroll
        for (int j = 0; j < 4; ++j)
            zL[j][w * 16 + fr] = acc[j] + b2[ch0 + j];
    }
    __syncthreads();
    // h-lerp into tmp (iw<8 so tmp[..][7] is valid for unconditional i0+1 reads;
    // zL cols 0..55 used, all initialized)
    for (int idx = t; idx < 1792; idx += 256) {   // 4c x 56h x 8iw
        int c = idx >> 9;            // idx/512? no: 56*8=448 per c
        c = idx / 448;
        int rem = idx - c * 448;
        int h = rem >> 3, iw = rem & 7;
        int i0 = wi[h]; float f = wf[h];
        float z0 = zL[c][i0 * 7 + iw];
        tmp[c][h][iw] = z0 + f * (zL[c][i0 * 7 + 7 + iw] - z0);
    }
    __syncthreads();
    size_t obase = ((size_t)(Bi * 384 + ch0)) * (size_t)NPIX;
    for (int q = t; q < 3136; q += 256) {         // 4 planes x 784 quads
        int c = q / 784, rem = q - c * 784;
        int h = rem / 14, qw = rem - h * 14;
        const float* tr = &tmp[c][h][0];
        int wbase = qw * 4;
        vf4 o4;
#pragma unroll
        for (int j = 0; j < 4; ++j) {
            int i0 = wi[wbase + j];
            float f = wf[wbase + j];
            float t0 = tr[i0];
            o4[j] = t0 + f * (tr[i0 + 1] - t0);
        }
        __builtin_nontemporal_store(o4,
            reinterpret_cast<vf4*>(out + obase + (size_t)q * 4));
    }
}

// ---------------------------------------------------------------------------
extern "C" void kernel_launch(void* const* d_in, const int* in_sizes, int n_in,
                              void* d_out, int out_size, void* d_ws, size_t ws_size,
                              hipStream_t stream) {
    const float* x      = (const float*)d_in[0];
    const float* proj_w = (const float*)d_in[1];
    const float* proj_b = (const float*)d_in[2];
    const float* alpha  = (const float*)d_in[3];
    const float* beta   = (const float*)d_in[4];
    const float* w2     = (const float*)d_in[5];
    const float* b2     = (const float*)d_in[6];
    float* out = (float*)d_out;
    float* ws  = (float*)d_ws;

    unsigned short* Whi1  = (unsigned short*)(ws);                   // 737,280 u16
    unsigned short* Wlo1  = (unsigned short*)(ws + (size_t)368640);
    unsigned short* Xhi   = (unsigned short*)(ws + (size_t)737280);  // 344,064 u16
    unsigned short* Xlo   = (unsigned short*)(ws + (size_t)909312);
    unsigned short* Whi2  = (unsigned short*)(ws + (size_t)1081344); // 147,456 u16
    unsigned short* Wlo2  = (unsigned short*)(ws + (size_t)1155072);
    unsigned short* osThi = (unsigned short*)(ws + (size_t)1228800); // 393,216 u16
    unsigned short* osTlo = (unsigned short*)(ws + (size_t)1425408);
    // total ws ~6.5 MB

    k_front<<<dim3(9600), 256, 0, stream>>>(x, proj_w, w2, Xhi, Xlo, Whi1, Wlo1, Whi2, Wlo2);
    k_fuse <<<dim3(128),  512, 0, stream>>>(Whi1, Wlo1, Xhi, Xlo, proj_b, alpha, beta, osThi, osTlo);
    k_tail <<<dim3(1536), 256, 0, stream>>>(Whi2, Wlo2, osThi, osTlo, b2, out);
}

// Round 15
// 69.768 us; speedup vs baseline: 2.0633x; 1.0238x over previous
//
#include <hip/hip_runtime.h>
#include <math.h>

#define CIN    384
#define NPIX   3136      // 56*56

typedef float vf4 __attribute__((ext_vector_type(4)));
typedef __attribute__((ext_vector_type(4))) float f32x4;
typedef __attribute__((ext_vector_type(8))) short bf16x8;
typedef __attribute__((ext_vector_type(8))) unsigned short u16x8;

__device__ __forceinline__ unsigned short f2bf(float f) {
    unsigned u = __float_as_uint(f);
    u = (u + 0x7FFF + ((u >> 16) & 1)) >> 16;
    return (unsigned short)u;
}
__device__ __forceinline__ float bf2f(unsigned short h) {
    return __uint_as_float(((unsigned)h) << 16);
}
__device__ __forceinline__ float dot4(const float* a, const float* b) {
    float4 x = *reinterpret_cast<const float4*>(a);
    float4 y = *reinterpret_cast<const float4*>(b);
    return x.x * y.x + x.y * y.y + x.z * y.z + x.w * y.w;
}

// ---------------------------------------------------------------------------
// k_front: [0,6144) pool x -> Xhi/Xlo bf16 transposed [p=848][k=384]
//          [6144,9024) split proj_w ; [9024,9600) split proj2_w
// (measured r13: ~12 us ~= 77MB read floor -> at roofline, unchanged)
// ---------------------------------------------------------------------------
__global__ __launch_bounds__(256) void k_front(const float* __restrict__ x,
                                               const float* __restrict__ W1,
                                               const float* __restrict__ W2,
                                               unsigned short* __restrict__ Xhi,
                                               unsigned short* __restrict__ Xlo,
                                               unsigned short* __restrict__ Whi1,
                                               unsigned short* __restrict__ Wlo1,
                                               unsigned short* __restrict__ Whi2,
                                               unsigned short* __restrict__ Wlo2) {
    int blk = blockIdx.x;
    int t = threadIdx.x;
    if (blk >= 9024) {           // W2 split
        int i = (blk - 9024) * 256 + t;
        float w = W2[i];
        unsigned short hi = f2bf(w);
        Whi2[i] = hi;
        Wlo2[i] = f2bf(w - bf2f(hi));
        return;
    }
    if (blk >= 6144) {           // W1 split
        int i = (blk - 6144) * 256 + t;
        float w = W1[i];
        unsigned short hi = f2bf(w);
        Whi1[i] = hi;
        Wlo1[i] = f2bf(w - bf2f(hi));
        return;
    }
    int Bi = blk / CIN;
    int ch = blk - Bi * CIN;
    __shared__ float ps[56][14];
    __shared__ float s14[14][14];
    const float* xp = x + (size_t)(Bi * CIN + ch) * NPIX;
    for (int p = t; p < 784; p += 256) {
        int row = p / 14, cb = p % 14;
        const vf4 v = __builtin_nontemporal_load(
            reinterpret_cast<const vf4*>(xp + row * 56 + cb * 4));
        ps[row][cb] = v.x + v.y + v.z + v.w;
    }
    __syncthreads();
    if (t < 196) {
        int ri = t / 14, cb = t % 14;
        s14[ri][cb] = ps[4*ri][cb] + ps[4*ri+1][cb] + ps[4*ri+2][cb] + ps[4*ri+3][cb];
    }
    __syncthreads();
    if (t < 49) {
        int i = t / 7, j = t % 7;
        float s = (s14[2*i][2*j] + s14[2*i][2*j+1] + s14[2*i+1][2*j] + s14[2*i+1][2*j+1])
                  * (1.0f / 64.0f);
        int p = Bi * 49 + t;
        unsigned short hi = f2bf(s);
        Xhi[(size_t)p * 384 + ch] = hi;
        Xlo[(size_t)p * 384 + ch] = f2bf(s - bf2f(hi));
    } else if (t >= 64 && t < 68) {
        int m = t - 64;
        int mi = m / 2, mj = m % 2;
        float s = 0.f;
        for (int ri = 7*mi; ri < 7*mi + 7; ++ri)
            for (int cb = 7*mj; cb < 7*mj + 7; ++cb)
                s += s14[ri][cb];
        s *= (1.0f / 784.0f);
        int p = 784 + Bi * 4 + m;
        unsigned short hi = f2bf(s);
        Xhi[(size_t)p * 384 + ch] = hi;
        Xlo[(size_t)p * 384 + ch] = f2bf(s - bf2f(hi));
    }
}

// ---------------------------------------------------------------------------
// k_fuse: per-(Bi,head): y = W1@x+b (240x53, bf16x3 MFMA), DUAL LDS layouts
//         yT[240][72] + yN[53][244]; attention dots via ds_read_b128 (float4).
// ---------------------------------------------------------------------------
__global__ __launch_bounds__(512) void k_fuse(
        const unsigned short* __restrict__ Whi, const unsigned short* __restrict__ Wlo,
        const unsigned short* __restrict__ Xhi, const unsigned short* __restrict__ Xlo,
        const float* __restrict__ proj_b,
        const float* __restrict__ alpha, const float* __restrict__ beta,
        unsigned short* __restrict__ osThi, unsigned short* __restrict__ osTlo) {
    int bb = blockIdx.x;           // 128
    int Bi = bb >> 3, head = bb & 7;
    __shared__ float yT[240 * 72];   // row-major; staging aliased (48.6KB<69.1KB)
    __shared__ float yN[53 * 244];   // transposed copy [col][row]
    __shared__ float e0[4 * 52], memb[4 * 52];
    __shared__ float msum[4];
    __shared__ float agg[8][48];
    __shared__ float anorm[8], pnorm[49];
    __shared__ float simL[8 * 49];
    __shared__ float assignW[8 * 49];
    unsigned short* sAh = (unsigned short*)yT;   // 240*40
    unsigned short* sAl = sAh + 9600;
    unsigned short* sBh = sAl + 9600;            // 64*40
    unsigned short* sBl = sBh + 2560;
    int t = threadIdx.x;
    int lane = t & 63, w = t >> 6;
    int fr = lane & 15, fq = lane >> 4;

    int row0 = t >> 2, ko0 = (t & 3) * 8;
    int g0 = row0 / 48, cc0 = row0 - g0 * 48;
    size_t aoff0 = (size_t)(g0 * 384 + head * 48 + cc0) * 384 + ko0;
    int c1 = t + 512;
    int row1 = c1 >> 2, ko1 = (c1 & 3) * 8;
    int g1 = row1 / 48, cc1 = row1 - g1 * 48;
    size_t aoff1 = (size_t)(g1 * 384 + head * 48 + cc1) * 384 + ko1;  // t<448
    int bko = (t & 3) * 8;
    int brow = t >> 2;
    int bp = brow < 49 ? Bi * 49 + brow : 784 + Bi * 4 + (brow - 49);
    size_t boff = (size_t)bp * 384 + bko;                              // t<212

    u16x8 rAh0, rAl0, rAh1, rAl1, rBh, rBl;
    rAh0 = *(const u16x8*)(Whi + aoff0);
    rAl0 = *(const u16x8*)(Wlo + aoff0);
    if (t < 448) { rAh1 = *(const u16x8*)(Whi + aoff1); rAl1 = *(const u16x8*)(Wlo + aoff1); }
    if (t < 212) { rBh  = *(const u16x8*)(Xhi + boff);  rBl  = *(const u16x8*)(Xlo + boff); }

    f32x4 acc[2][4] = {};
    for (int step = 0; step < 12; ++step) {
        *(u16x8*)&sAh[row0 * 40 + ko0] = rAh0;
        *(u16x8*)&sAl[row0 * 40 + ko0] = rAl0;
        if (t < 448) {
            *(u16x8*)&sAh[row1 * 40 + ko1] = rAh1;
            *(u16x8*)&sAl[row1 * 40 + ko1] = rAl1;
        }
        if (t < 212) {
            *(u16x8*)&sBh[brow * 40 + bko] = rBh;
            *(u16x8*)&sBl[brow * 40 + bko] = rBl;
        }
        __syncthreads();
        if (step < 11) {
            int k0 = (step + 1) * 32;
            rAh0 = *(const u16x8*)(Whi + aoff0 + k0);
            rAl0 = *(const u16x8*)(Wlo + aoff0 + k0);
            if (t < 448) { rAh1 = *(const u16x8*)(Whi + aoff1 + k0); rAl1 = *(const u16x8*)(Wlo + aoff1 + k0); }
            if (t < 212) { rBh  = *(const u16x8*)(Xhi + boff + k0);  rBl  = *(const u16x8*)(Xlo + boff + k0); }
        }
        bf16x8 bh[4], bl[4];
#pragma unroll
        for (int nt = 0; nt < 4; ++nt) {
            int r = nt * 16 + fr;
            bh[nt] = *(const bf16x8*)&sBh[r * 40 + fq * 8];
            bl[nt] = *(const bf16x8*)&sBl[r * 40 + fq * 8];
        }
#pragma unroll
        for (int mi = 0; mi < 2; ++mi) {
            int mt = 2 * w + mi;
            if (mt < 15) {
                int r = mt * 16 + fr;
                bf16x8 ah = *(const bf16x8*)&sAh[r * 40 + fq * 8];
                bf16x8 al = *(const bf16x8*)&sAl[r * 40 + fq * 8];
#pragma unroll
                for (int nt = 0; nt < 4; ++nt) {
                    acc[mi][nt] = __builtin_amdgcn_mfma_f32_16x16x32_bf16(ah, bh[nt], acc[mi][nt], 0, 0, 0);
                    acc[mi][nt] = __builtin_amdgcn_mfma_f32_16x16x32_bf16(ah, bl[nt], acc[mi][nt], 0, 0, 0);
                    acc[mi][nt] = __builtin_amdgcn_mfma_f32_16x16x32_bf16(al, bh[nt], acc[mi][nt], 0, 0, 0);
                }
            }
        }
        __syncthreads();
    }
    // C-write into BOTH layouts. C/D: col=lane&15, row=(lane>>4)*4+j
#pragma unroll
    for (int mi = 0; mi < 2; ++mi) {
        int mt = 2 * w + mi;
        if (mt < 15) {
#pragma unroll
            for (int j = 0; j < 4; ++j) {
                int m = mt * 16 + fq * 4 + j;
                int g = m / 48, cc = m - g * 48;
                float bb = proj_b[g * 384 + head * 48 + cc];
#pragma unroll
                for (int nt = 0; nt < 4; ++nt) {
                    int col = nt * 16 + fr;
                    float v = acc[mi][nt][j] + bb;
                    yT[m * 72 + col] = v;
                    if (col < 53) yN[col * 244 + m] = v;
                }
            }
        }
    }
    __syncthreads();

    // ---- attention. rows: p=0..47 | k0=48 | v0=96 | k1=144 | v1=192
    //      cols: n<49 agents; 49+m clusters
    const float scale = 0.14433756729740643f;  // 1/sqrt(48)
    // P1: scores via yN (contiguous cc), 12x dot4
    if (t < 392) {
        int i = t / 196, r = t % 196;
        int m = r / 49, n = r % 49;
        const float* kn = yN + n * 244 + 48 + 96 * i;
        const float* kc = yN + (49 + m) * 244 + 48 + 96 * i;
        float s = 0.f;
#pragma unroll
        for (int j = 0; j < 12; ++j) s += dot4(kc + j * 4, kn + j * 4);
        s *= scale;
        if (i == 0) e0[m * 52 + n] = s; else memb[m * 52 + n] = s;
    }
    __syncthreads();
    // P2: module-0 row softmax (waves 0-3); module-1 column softmax (wave 4)
    if (w < 4) {
        float v = (lane < 49) ? e0[w * 52 + lane] : -1e30f;
        float mx = v;
#pragma unroll
        for (int off = 32; off; off >>= 1) mx = fmaxf(mx, __shfl_xor(mx, off));
        float e = (lane < 49) ? __expf(v - mx) : 0.f;
        float s = e;
#pragma unroll
        for (int off = 32; off; off >>= 1) s += __shfl_xor(s, off);
        if (lane < 49) e0[w * 52 + lane] = e / s;
    } else if (w == 4 && lane < 49) {
        int n = lane;
        float a0 = memb[n], a1 = memb[52 + n], a2 = memb[104 + n], a3 = memb[156 + n];
        float mx = fmaxf(fmaxf(a0, a1), fmaxf(a2, a3));
        float x0 = __expf(a0 - mx), x1 = __expf(a1 - mx);
        float x2 = __expf(a2 - mx), x3 = __expf(a3 - mx);
        float s = x0 + x1 + x2 + x3;
        memb[n] = x0 / s; memb[52 + n] = x1 / s; memb[104 + n] = x2 / s; memb[156 + n] = x3 / s;
    }
    __syncthreads();
    // P3: msum (waves 4-7)
    if (w >= 4) {
        int m = w - 4;
        float v = (lane < 49) ? memb[m * 52 + lane] : 0.f;
#pragma unroll
        for (int off = 32; off; off >>= 1) v += __shfl_xor(v, off);
        if (lane == 0) msum[m] = v;
    }
    __syncthreads();
    // P4: agg via yT rows (contiguous n) + padded prob rows, 12x dot4
    if (t < 384) {
        int row = t / 48, cc = t % 48;
        float a = 0.f;
        if (row < 4) {
            const float* vr = yT + (96 + cc) * 72;
            const float* pe = e0 + row * 52;
#pragma unroll
            for (int j = 0; j < 12; ++j) a += dot4(pe + j * 4, vr + j * 4);
            a += pe[48] * vr[48];
            agg[row][cc] = a + vr[49 + row];
        } else {
            int m = row - 4;
            const float* vr = yT + (192 + cc) * 72;
            const float* pe = memb + m * 52;
#pragma unroll
            for (int j = 0; j < 12; ++j) a += dot4(pe + j * 4, vr + j * 4);
            a += pe[48] * vr[48];
            agg[row][cc] = a / (msum[m] + 1e-6f) + vr[49 + m];
        }
    }
    __syncthreads();
    // P5: anorm by waves; pnorm via yN 12x dot4
    {
        float v = 0.f;
        if (lane < 48) { float a = agg[w][lane]; v = a * a; }
#pragma unroll
        for (int off = 32; off; off >>= 1) v += __shfl_xor(v, off);
        if (lane == 0) anorm[w] = sqrtf(v) + 1e-6f;
    }
    if (t < 49) {
        const float* pn = yN + t * 244;
        float s = 0.f;
#pragma unroll
        for (int j = 0; j < 12; ++j) s += dot4(pn + j * 4, pn + j * 4);
        pnorm[t] = sqrtf(s) + 1e-6f;
    }
    __syncthreads();
    // P6: similarity via agg rows + yN cols, 12x dot4
    if (t < 392) {
        int m = t / 49, n = t - m * 49;
        const float* am = &agg[m][0];
        const float* pn = yN + n * 244;
        float dot = 0.f;
#pragma unroll
        for (int j = 0; j < 12; ++j) dot += dot4(am + j * 4, pn + j * 4);
        simL[m * 49 + n] = alpha[m] * (dot / (anorm[m] * pnorm[n])) + beta[m];
    }
    __syncthreads();
    // P7: assignment softmax over m
    if (t < 49) {
        int n = t;
        float mx = -1e30f, e[8];
#pragma unroll
        for (int m = 0; m < 8; ++m) mx = fmaxf(mx, simL[m * 49 + n]);
        float ssum = 0.f;
#pragma unroll
        for (int m = 0; m < 8; ++m) { e[m] = __expf(simL[m * 49 + n] - mx); ssum += e[m]; }
        float inv = 1.f / ssum;
#pragma unroll
        for (int m = 0; m < 8; ++m) assignW[m * 49 + n] = e[m] * inv;
    }
    __syncthreads();
    // P8: osT write (bf16 hi/lo, n padded to 64)
    for (int idx = t; idx < 3072; idx += 512) {
        int n = idx / 48, cc = idx - n * 48;
        float s = 0.f;
        if (n < 49) {
#pragma unroll
            for (int m = 0; m < 8; ++m) s += agg[m][cc] * assignW[m * 49 + n];
        }
        size_t o = ((size_t)(Bi * 64 + n)) * 384 + head * 48 + cc;
        unsigned short hi = f2bf(s);
        osThi[o] = hi;
        osTlo[o] = f2bf(s - bf2f(hi));
    }
}

// ---------------------------------------------------------------------------
// k_tail v3: == r14's v2 but PLAIN stores (NT hypothesis A/B).
// z = W2 @ osT via bf16x3 MFMA (LDS-staged), table-driven bilinear upsample.
// ---------------------------------------------------------------------------
__global__ __launch_bounds__(256) void k_tail(
        const unsigned short* __restrict__ Whi2, const unsigned short* __restrict__ Wlo2,
        const unsigned short* __restrict__ osThi, const unsigned short* __restrict__ osTlo,
        const float* __restrict__ b2, float* __restrict__ out) {
    int blk = blockIdx.x;          // 1536 = 16 * 96
    int Bi = blk / 96, cg = blk - Bi * 96;
    int ch0 = cg * 4;
    __shared__ unsigned short sAh[16 * 40], sAl[16 * 40];
    __shared__ unsigned short sBh[64 * 40], sBl[64 * 40];
    __shared__ float zL[4][64];
    __shared__ float tmp[4][56][9];   // stride 9: bank-friendly
    __shared__ float wf[56];
    __shared__ int   wi[56];
    int t = threadIdx.x;
    int lane = t & 63, w = t >> 6;
    int fr = lane & 15, fq = lane >> 4;
    if (t < 56) {
        float s = (t - 3.5f) * 0.125f;
        int i0; float f;
        if (s <= 0.f)      { i0 = 0; f = 0.f; }
        else if (s >= 6.f) { i0 = 6; f = 0.f; }
        else               { i0 = (int)s; f = s - (float)i0; }
        wi[t] = i0; wf[t] = f;
    }
    for (int idx = t; idx < 480; idx += 256) {   // zero A pad rows 4..15
        int r = 4 + idx / 40, c = idx % 40;
        sAh[r * 40 + c] = 0; sAl[r * 40 + c] = 0;
    }
    int brow = t >> 2, bko = (t & 3) * 8;
    size_t boff = ((size_t)(Bi * 64 + brow)) * 384 + bko;
    f32x4 acc = {0, 0, 0, 0};
    for (int k0 = 0; k0 < 384; k0 += 32) {
        if (t < 16) {
            int arow = t >> 2, ako = (t & 3) * 8;
            size_t aoff = (size_t)(ch0 + arow) * 384 + k0 + ako;
            *(u16x8*)&sAh[arow * 40 + ako] = *(const u16x8*)(Whi2 + aoff);
            *(u16x8*)&sAl[arow * 40 + ako] = *(const u16x8*)(Wlo2 + aoff);
        }
        *(u16x8*)&sBh[brow * 40 + bko] = *(const u16x8*)(osThi + boff + k0);
        *(u16x8*)&sBl[brow * 40 + bko] = *(const u16x8*)(osTlo + boff + k0);
        __syncthreads();
        bf16x8 ah = *(const bf16x8*)&sAh[fr * 40 + fq * 8];
        bf16x8 al = *(const bf16x8*)&sAl[fr * 40 + fq * 8];
        int rb = w * 16 + fr;
        bf16x8 bh = *(const bf16x8*)&sBh[rb * 40 + fq * 8];
        bf16x8 bl = *(const bf16x8*)&sBl[rb * 40 + fq * 8];
        acc = __builtin_amdgcn_mfma_f32_16x16x32_bf16(ah, bh, acc, 0, 0, 0);
        acc = __builtin_amdgcn_mfma_f32_16x16x32_bf16(ah, bl, acc, 0, 0, 0);
        acc = __builtin_amdgcn_mfma_f32_16x16x32_bf16(al, bh, acc, 0, 0, 0);
        __syncthreads();
    }
    if (fq == 0) {
#pragma unroll
        for (int j = 0; j < 4; ++j)
            zL[j][w * 16 + fr] = acc[j] + b2[ch0 + j];
    }
    __syncthreads();
    for (int idx = t; idx < 1792; idx += 256) {   // 4c x 56h x 8iw
        int c = idx / 448;
        int rem = idx - c * 448;
        int h = rem >> 3, iw = rem & 7;
        int i0 = wi[h]; float f = wf[h];
        float z0 = zL[c][i0 * 7 + iw];
        tmp[c][h][iw] = z0 + f * (zL[c][i0 * 7 + 7 + iw] - z0);
    }
    __syncthreads();
    size_t obase = ((size_t)(Bi * 384 + ch0)) * (size_t)NPIX;
    for (int q = t; q < 3136; q += 256) {         // 4 planes x 784 quads
        int c = q / 784, rem = q - c * 784;
        int h = rem / 14, qw = rem - h * 14;
        const float* tr = &tmp[c][h][0];
        int wbase = qw * 4;
        vf4 o4;
#pragma unroll
        for (int j = 0; j < 4; ++j) {
            int i0 = wi[wbase + j];
            float f = wf[wbase + j];
            float t0 = tr[i0];
            o4[j] = t0 + f * (tr[i0 + 1] - t0);
        }
        *reinterpret_cast<vf4*>(out + obase + (size_t)q * 4) = o4;  // plain store
    }
}

// ---------------------------------------------------------------------------
extern "C" void kernel_launch(void* const* d_in, const int* in_sizes, int n_in,
                              void* d_out, int out_size, void* d_ws, size_t ws_size,
                              hipStream_t stream) {
    const float* x      = (const float*)d_in[0];
    const float* proj_w = (const float*)d_in[1];
    const float* proj_b = (const float*)d_in[2];
    const float* alpha  = (const float*)d_in[3];
    const float* beta   = (const float*)d_in[4];
    const float* w2     = (const float*)d_in[5];
    const float* b2     = (const float*)d_in[6];
    float* out = (float*)d_out;
    float* ws  = (float*)d_ws;

    unsigned short* Whi1  = (unsigned short*)(ws);                   // 737,280 u16
    unsigned short* Wlo1  = (unsigned short*)(ws + (size_t)368640);
    unsigned short* Xhi   = (unsigned short*)(ws + (size_t)737280);  // 344,064 u16
    unsigned short* Xlo   = (unsigned short*)(ws + (size_t)909312);
    unsigned short* Whi2  = (unsigned short*)(ws + (size_t)1081344); // 147,456 u16
    unsigned short* Wlo2  = (unsigned short*)(ws + (size_t)1155072);
    unsigned short* osThi = (unsigned short*)(ws + (size_t)1228800); // 393,216 u16
    unsigned short* osTlo = (unsigned short*)(ws + (size_t)1425408);
    // total ws ~6.5 MB

    k_front<<<dim3(9600), 256, 0, stream>>>(x, proj_w, w2, Xhi, Xlo, Whi1, Wlo1, Whi2, Wlo2);
    k_fuse <<<dim3(128),  512, 0, stream>>>(Whi1, Wlo1, Xhi, Xlo, proj_b, alpha, beta, osThi, osTlo);
    k_tail <<<dim3(1536), 256, 0, stream>>>(Whi2, Wlo2, osThi, osTlo, b2, out);
}

// Round 16
// 69.333 us; speedup vs baseline: 2.0762x; 1.0063x over previous
//
#include <hip/hip_runtime.h>
#include <math.h>

#define CIN    384
#define NPIX   3136      // 56*56

typedef float vf4 __attribute__((ext_vector_type(4)));
typedef __attribute__((ext_vector_type(4))) float f32x4;
typedef __attribute__((ext_vector_type(8))) short bf16x8;
typedef __attribute__((ext_vector_type(8))) unsigned short u16x8;

__device__ __forceinline__ unsigned short f2bf(float f) {
    unsigned u = __float_as_uint(f);
    u = (u + 0x7FFF + ((u >> 16) & 1)) >> 16;
    return (unsigned short)u;
}
__device__ __forceinline__ float bf2f(unsigned short h) {
    return __uint_as_float(((unsigned)h) << 16);
}
__device__ __forceinline__ float dot4(const float* a, const float* b) {
    float4 x = *reinterpret_cast<const float4*>(a);
    float4 y = *reinterpret_cast<const float4*>(b);
    return x.x * y.x + x.y * y.y + x.z * y.z + x.w * y.w;
}

// ---------------------------------------------------------------------------
// k_front: [0,6144) pool x -> Xhi/Xlo bf16 transposed [p=848][k=384]
//          [6144,9024) split proj_w ; [9024,9600) split proj2_w
// (measured r13: ~12 us ~= 77MB read floor -> at roofline, unchanged)
// ---------------------------------------------------------------------------
__global__ __launch_bounds__(256) void k_front(const float* __restrict__ x,
                                               const float* __restrict__ W1,
                                               const float* __restrict__ W2,
                                               unsigned short* __restrict__ Xhi,
                                               unsigned short* __restrict__ Xlo,
                                               unsigned short* __restrict__ Whi1,
                                               unsigned short* __restrict__ Wlo1,
                                               unsigned short* __restrict__ Whi2,
                                               unsigned short* __restrict__ Wlo2) {
    int blk = blockIdx.x;
    int t = threadIdx.x;
    if (blk >= 9024) {           // W2 split
        int i = (blk - 9024) * 256 + t;
        float w = W2[i];
        unsigned short hi = f2bf(w);
        Whi2[i] = hi;
        Wlo2[i] = f2bf(w - bf2f(hi));
        return;
    }
    if (blk >= 6144) {           // W1 split
        int i = (blk - 6144) * 256 + t;
        float w = W1[i];
        unsigned short hi = f2bf(w);
        Whi1[i] = hi;
        Wlo1[i] = f2bf(w - bf2f(hi));
        return;
    }
    int Bi = blk / CIN;
    int ch = blk - Bi * CIN;
    __shared__ float ps[56][14];
    __shared__ float s14[14][14];
    const float* xp = x + (size_t)(Bi * CIN + ch) * NPIX;
    for (int p = t; p < 784; p += 256) {
        int row = p / 14, cb = p % 14;
        const vf4 v = __builtin_nontemporal_load(
            reinterpret_cast<const vf4*>(xp + row * 56 + cb * 4));
        ps[row][cb] = v.x + v.y + v.z + v.w;
    }
    __syncthreads();
    if (t < 196) {
        int ri = t / 14, cb = t % 14;
        s14[ri][cb] = ps[4*ri][cb] + ps[4*ri+1][cb] + ps[4*ri+2][cb] + ps[4*ri+3][cb];
    }
    __syncthreads();
    if (t < 49) {
        int i = t / 7, j = t % 7;
        float s = (s14[2*i][2*j] + s14[2*i][2*j+1] + s14[2*i+1][2*j] + s14[2*i+1][2*j+1])
                  * (1.0f / 64.0f);
        int p = Bi * 49 + t;
        unsigned short hi = f2bf(s);
        Xhi[(size_t)p * 384 + ch] = hi;
        Xlo[(size_t)p * 384 + ch] = f2bf(s - bf2f(hi));
    } else if (t >= 64 && t < 68) {
        int m = t - 64;
        int mi = m / 2, mj = m % 2;
        float s = 0.f;
        for (int ri = 7*mi; ri < 7*mi + 7; ++ri)
            for (int cb = 7*mj; cb < 7*mj + 7; ++cb)
                s += s14[ri][cb];
        s *= (1.0f / 784.0f);
        int p = 784 + Bi * 4 + m;
        unsigned short hi = f2bf(s);
        Xhi[(size_t)p * 384 + ch] = hi;
        Xlo[(size_t)p * 384 + ch] = f2bf(s - bf2f(hi));
    }
}

// ---------------------------------------------------------------------------
// k_fuse: per-(Bi,head): y = W1@x+b (240x53, bf16x3 MFMA), DUAL LDS layouts
//   yT stride 76 (gcd(76%32,32)=4 -> 8 bank-groups, ~2x fewer conflicts than
//   72's gcd-8) + yN[53][244]; attention dots via ds_read_b128.
//   P8 osT write vectorized u16x8.
// ---------------------------------------------------------------------------
__global__ __launch_bounds__(512) void k_fuse(
        const unsigned short* __restrict__ Whi, const unsigned short* __restrict__ Wlo,
        const unsigned short* __restrict__ Xhi, const unsigned short* __restrict__ Xlo,
        const float* __restrict__ proj_b,
        const float* __restrict__ alpha, const float* __restrict__ beta,
        unsigned short* __restrict__ osThi, unsigned short* __restrict__ osTlo) {
    int bb = blockIdx.x;           // 128
    int Bi = bb >> 3, head = bb & 7;
    __shared__ float yT[240 * 76];   // row-major, stride 76; staging aliased
    __shared__ float yN[53 * 244];   // transposed copy [col][row]
    __shared__ float e0[4 * 52], memb[4 * 52];
    __shared__ float msum[4];
    __shared__ float agg[8][48];
    __shared__ float anorm[8], pnorm[49];
    __shared__ float simL[8 * 49];
    __shared__ float assignW[8 * 49];
    unsigned short* sAh = (unsigned short*)yT;   // 240*40
    unsigned short* sAl = sAh + 9600;
    unsigned short* sBh = sAl + 9600;            // 64*40
    unsigned short* sBl = sBh + 2560;
    int t = threadIdx.x;
    int lane = t & 63, w = t >> 6;
    int fr = lane & 15, fq = lane >> 4;

    int row0 = t >> 2, ko0 = (t & 3) * 8;
    int g0 = row0 / 48, cc0 = row0 - g0 * 48;
    size_t aoff0 = (size_t)(g0 * 384 + head * 48 + cc0) * 384 + ko0;
    int c1 = t + 512;
    int row1 = c1 >> 2, ko1 = (c1 & 3) * 8;
    int g1 = row1 / 48, cc1 = row1 - g1 * 48;
    size_t aoff1 = (size_t)(g1 * 384 + head * 48 + cc1) * 384 + ko1;  // t<448
    int bko = (t & 3) * 8;
    int brow = t >> 2;
    int bp = brow < 49 ? Bi * 49 + brow : 784 + Bi * 4 + (brow - 49);
    size_t boff = (size_t)bp * 384 + bko;                              // t<212

    u16x8 rAh0, rAl0, rAh1, rAl1, rBh, rBl;
    rAh0 = *(const u16x8*)(Whi + aoff0);
    rAl0 = *(const u16x8*)(Wlo + aoff0);
    if (t < 448) { rAh1 = *(const u16x8*)(Whi + aoff1); rAl1 = *(const u16x8*)(Wlo + aoff1); }
    if (t < 212) { rBh  = *(const u16x8*)(Xhi + boff);  rBl  = *(const u16x8*)(Xlo + boff); }

    f32x4 acc[2][4] = {};
    for (int step = 0; step < 12; ++step) {
        *(u16x8*)&sAh[row0 * 40 + ko0] = rAh0;
        *(u16x8*)&sAl[row0 * 40 + ko0] = rAl0;
        if (t < 448) {
            *(u16x8*)&sAh[row1 * 40 + ko1] = rAh1;
            *(u16x8*)&sAl[row1 * 40 + ko1] = rAl1;
        }
        if (t < 212) {
            *(u16x8*)&sBh[brow * 40 + bko] = rBh;
            *(u16x8*)&sBl[brow * 40 + bko] = rBl;
        }
        __syncthreads();
        if (step < 11) {
            int k0 = (step + 1) * 32;
            rAh0 = *(const u16x8*)(Whi + aoff0 + k0);
            rAl0 = *(const u16x8*)(Wlo + aoff0 + k0);
            if (t < 448) { rAh1 = *(const u16x8*)(Whi + aoff1 + k0); rAl1 = *(const u16x8*)(Wlo + aoff1 + k0); }
            if (t < 212) { rBh  = *(const u16x8*)(Xhi + boff + k0);  rBl  = *(const u16x8*)(Xlo + boff + k0); }
        }
        bf16x8 bh[4], bl[4];
#pragma unroll
        for (int nt = 0; nt < 4; ++nt) {
            int r = nt * 16 + fr;
            bh[nt] = *(const bf16x8*)&sBh[r * 40 + fq * 8];
            bl[nt] = *(const bf16x8*)&sBl[r * 40 + fq * 8];
        }
#pragma unroll
        for (int mi = 0; mi < 2; ++mi) {
            int mt = 2 * w + mi;
            if (mt < 15) {
                int r = mt * 16 + fr;
                bf16x8 ah = *(const bf16x8*)&sAh[r * 40 + fq * 8];
                bf16x8 al = *(const bf16x8*)&sAl[r * 40 + fq * 8];
#pragma unroll
                for (int nt = 0; nt < 4; ++nt) {
                    acc[mi][nt] = __builtin_amdgcn_mfma_f32_16x16x32_bf16(ah, bh[nt], acc[mi][nt], 0, 0, 0);
                    acc[mi][nt] = __builtin_amdgcn_mfma_f32_16x16x32_bf16(ah, bl[nt], acc[mi][nt], 0, 0, 0);
                    acc[mi][nt] = __builtin_amdgcn_mfma_f32_16x16x32_bf16(al, bh[nt], acc[mi][nt], 0, 0, 0);
                }
            }
        }
        __syncthreads();
    }
    // C-write into BOTH layouts. C/D: col=lane&15, row=(lane>>4)*4+j
#pragma unroll
    for (int mi = 0; mi < 2; ++mi) {
        int mt = 2 * w + mi;
        if (mt < 15) {
#pragma unroll
            for (int j = 0; j < 4; ++j) {
                int m = mt * 16 + fq * 4 + j;
                int g = m / 48, cc = m - g * 48;
                float bb = proj_b[g * 384 + head * 48 + cc];
#pragma unroll
                for (int nt = 0; nt < 4; ++nt) {
                    int col = nt * 16 + fr;
                    float v = acc[mi][nt][j] + bb;
                    yT[m * 76 + col] = v;
                    if (col < 53) yN[col * 244 + m] = v;
                }
            }
        }
    }
    __syncthreads();

    // ---- attention. rows: p=0..47 | k0=48 | v0=96 | k1=144 | v1=192
    //      cols: n<49 agents; 49+m clusters
    const float scale = 0.14433756729740643f;  // 1/sqrt(48)
    // P1: scores via yN (contiguous cc), 12x dot4
    if (t < 392) {
        int i = t / 196, r = t % 196;
        int m = r / 49, n = r % 49;
        const float* kn = yN + n * 244 + 48 + 96 * i;
        const float* kc = yN + (49 + m) * 244 + 48 + 96 * i;
        float s = 0.f;
#pragma unroll
        for (int j = 0; j < 12; ++j) s += dot4(kc + j * 4, kn + j * 4);
        s *= scale;
        if (i == 0) e0[m * 52 + n] = s; else memb[m * 52 + n] = s;
    }
    __syncthreads();
    // P2: module-0 row softmax (waves 0-3); module-1 column softmax (wave 4)
    if (w < 4) {
        float v = (lane < 49) ? e0[w * 52 + lane] : -1e30f;
        float mx = v;
#pragma unroll
        for (int off = 32; off; off >>= 1) mx = fmaxf(mx, __shfl_xor(mx, off));
        float e = (lane < 49) ? __expf(v - mx) : 0.f;
        float s = e;
#pragma unroll
        for (int off = 32; off; off >>= 1) s += __shfl_xor(s, off);
        if (lane < 49) e0[w * 52 + lane] = e / s;
    } else if (w == 4 && lane < 49) {
        int n = lane;
        float a0 = memb[n], a1 = memb[52 + n], a2 = memb[104 + n], a3 = memb[156 + n];
        float mx = fmaxf(fmaxf(a0, a1), fmaxf(a2, a3));
        float x0 = __expf(a0 - mx), x1 = __expf(a1 - mx);
        float x2 = __expf(a2 - mx), x3 = __expf(a3 - mx);
        float s = x0 + x1 + x2 + x3;
        memb[n] = x0 / s; memb[52 + n] = x1 / s; memb[104 + n] = x2 / s; memb[156 + n] = x3 / s;
    }
    __syncthreads();
    // P3: msum (waves 4-7)
    if (w >= 4) {
        int m = w - 4;
        float v = (lane < 49) ? memb[m * 52 + lane] : 0.f;
#pragma unroll
        for (int off = 32; off; off >>= 1) v += __shfl_xor(v, off);
        if (lane == 0) msum[m] = v;
    }
    __syncthreads();
    // P4: agg via yT rows (stride 76) + padded prob rows, 12x dot4
    if (t < 384) {
        int row = t / 48, cc = t % 48;
        float a = 0.f;
        if (row < 4) {
            const float* vr = yT + (96 + cc) * 76;
            const float* pe = e0 + row * 52;
#pragma unroll
            for (int j = 0; j < 12; ++j) a += dot4(pe + j * 4, vr + j * 4);
            a += pe[48] * vr[48];
            agg[row][cc] = a + vr[49 + row];
        } else {
            int m = row - 4;
            const float* vr = yT + (192 + cc) * 76;
            const float* pe = memb + m * 52;
#pragma unroll
            for (int j = 0; j < 12; ++j) a += dot4(pe + j * 4, vr + j * 4);
            a += pe[48] * vr[48];
            agg[row][cc] = a / (msum[m] + 1e-6f) + vr[49 + m];
        }
    }
    __syncthreads();
    // P5: anorm by waves; pnorm via yN 12x dot4
    {
        float v = 0.f;
        if (lane < 48) { float a = agg[w][lane]; v = a * a; }
#pragma unroll
        for (int off = 32; off; off >>= 1) v += __shfl_xor(v, off);
        if (lane == 0) anorm[w] = sqrtf(v) + 1e-6f;
    }
    if (t < 49) {
        const float* pn = yN + t * 244;
        float s = 0.f;
#pragma unroll
        for (int j = 0; j < 12; ++j) s += dot4(pn + j * 4, pn + j * 4);
        pnorm[t] = sqrtf(s) + 1e-6f;
    }
    __syncthreads();
    // P6: similarity via agg rows + yN cols, 12x dot4
    if (t < 392) {
        int m = t / 49, n = t - m * 49;
        const float* am = &agg[m][0];
        const float* pn = yN + n * 244;
        float dot = 0.f;
#pragma unroll
        for (int j = 0; j < 12; ++j) dot += dot4(am + j * 4, pn + j * 4);
        simL[m * 49 + n] = alpha[m] * (dot / (anorm[m] * pnorm[n])) + beta[m];
    }
    __syncthreads();
    // P7: assignment softmax over m
    if (t < 49) {
        int n = t;
        float mx = -1e30f, e[8];
#pragma unroll
        for (int m = 0; m < 8; ++m) mx = fmaxf(mx, simL[m * 49 + n]);
        float ssum = 0.f;
#pragma unroll
        for (int m = 0; m < 8; ++m) { e[m] = __expf(simL[m * 49 + n] - mx); ssum += e[m]; }
        float inv = 1.f / ssum;
#pragma unroll
        for (int m = 0; m < 8; ++m) assignW[m * 49 + n] = e[m] * inv;
    }
    __syncthreads();
    // P8: osT write, VECTORIZED u16x8: t<384 -> n=t/6, 8 cols each
    if (t < 384) {
        int n = t / 6, c8 = (t - n * 6) * 8;
        u16x8 vh, vl;
#pragma unroll
        for (int j = 0; j < 8; ++j) {
            float s = 0.f;
            if (n < 49) {
                int cc = c8 + j;
#pragma unroll
                for (int m = 0; m < 8; ++m) s += agg[m][cc] * assignW[m * 49 + n];
            }
            unsigned short hi = f2bf(s);
            vh[j] = hi;
            vl[j] = f2bf(s - bf2f(hi));
        }
        size_t o = ((size_t)(Bi * 64 + n)) * 384 + head * 48 + c8;
        *(u16x8*)(osThi + o) = vh;
        *(u16x8*)(osTlo + o) = vl;
    }
}

// ---------------------------------------------------------------------------
// k_tail v4: z = W2 @ osT via bf16x3 MFMA (LDS-staged), table-driven bilinear
// upsample with PACKED int4/float4 per-quad weight tables (2 vec LDS reads
// per quad instead of 8 scalar), plain stores.
// ---------------------------------------------------------------------------
__global__ __launch_bounds__(256) void k_tail(
        const unsigned short* __restrict__ Whi2, const unsigned short* __restrict__ Wlo2,
        const unsigned short* __restrict__ osThi, const unsigned short* __restrict__ osTlo,
        const float* __restrict__ b2, float* __restrict__ out) {
    int blk = blockIdx.x;          // 1536 = 16 * 96
    int Bi = blk / 96, cg = blk - Bi * 96;
    int ch0 = cg * 4;
    __shared__ unsigned short sAh[16 * 40], sAl[16 * 40];
    __shared__ unsigned short sBh[64 * 40], sBl[64 * 40];
    __shared__ float zL[4][64];
    __shared__ float tmp[4][56][9];   // stride 9: bank-friendly
    __shared__ float wf[56];          // per-h fraction (h-lerp path)
    __shared__ int   wi[56];
    __shared__ int4   wi4[14];        // packed per-quad indices (w path)
    __shared__ float4 wf4[14];        // packed per-quad fractions
    int t = threadIdx.x;
    int lane = t & 63, w = t >> 6;
    int fr = lane & 15, fq = lane >> 4;
    if (t < 56) {
        float s = (t - 3.5f) * 0.125f;
        int i0; float f;
        if (s <= 0.f)      { i0 = 0; f = 0.f; }
        else if (s >= 6.f) { i0 = 6; f = 0.f; }
        else               { i0 = (int)s; f = s - (float)i0; }
        wi[t] = i0; wf[t] = f;
    }
    __syncthreads();   // wi/wf ready for packing
    if (t < 14) {
        int b = t * 4;
        wi4[t] = make_int4(wi[b], wi[b+1], wi[b+2], wi[b+3]);
        wf4[t] = make_float4(wf[b], wf[b+1], wf[b+2], wf[b+3]);
    }
    for (int idx = t; idx < 480; idx += 256) {   // zero A pad rows 4..15
        int r = 4 + idx / 40, c = idx % 40;
        sAh[r * 40 + c] = 0; sAl[r * 40 + c] = 0;
    }
    int brow = t >> 2, bko = (t & 3) * 8;
    size_t boff = ((size_t)(Bi * 64 + brow)) * 384 + bko;
    f32x4 acc = {0, 0, 0, 0};
    for (int k0 = 0; k0 < 384; k0 += 32) {
        if (t < 16) {
            int arow = t >> 2, ako = (t & 3) * 8;
            size_t aoff = (size_t)(ch0 + arow) * 384 + k0 + ako;
            *(u16x8*)&sAh[arow * 40 + ako] = *(const u16x8*)(Whi2 + aoff);
            *(u16x8*)&sAl[arow * 40 + ako] = *(const u16x8*)(Wlo2 + aoff);
        }
        *(u16x8*)&sBh[brow * 40 + bko] = *(const u16x8*)(osThi + boff + k0);
        *(u16x8*)&sBl[brow * 40 + bko] = *(const u16x8*)(osTlo + boff + k0);
        __syncthreads();
        bf16x8 ah = *(const bf16x8*)&sAh[fr * 40 + fq * 8];
        bf16x8 al = *(const bf16x8*)&sAl[fr * 40 + fq * 8];
        int rb = w * 16 + fr;
        bf16x8 bh = *(const bf16x8*)&sBh[rb * 40 + fq * 8];
        bf16x8 bl = *(const bf16x8*)&sBl[rb * 40 + fq * 8];
        acc = __builtin_amdgcn_mfma_f32_16x16x32_bf16(ah, bh, acc, 0, 0, 0);
        acc = __builtin_amdgcn_mfma_f32_16x16x32_bf16(ah, bl, acc, 0, 0, 0);
        acc = __builtin_amdgcn_mfma_f32_16x16x32_bf16(al, bh, acc, 0, 0, 0);
        __syncthreads();
    }
    if (fq == 0) {
#pragma unroll
        for (int j = 0; j < 4; ++j)
            zL[j][w * 16 + fr] = acc[j] + b2[ch0 + j];
    }
    __syncthreads();
    for (int idx = t; idx < 1792; idx += 256) {   // 4c x 56h x 8iw
        int c = idx / 448;
        int rem = idx - c * 448;
        int h = rem >> 3, iw = rem & 7;
        int i0 = wi[h]; float f = wf[h];
        float z0 = zL[c][i0 * 7 + iw];
        tmp[c][h][iw] = z0 + f * (zL[c][i0 * 7 + 7 + iw] - z0);
    }
    __syncthreads();
    size_t obase = ((size_t)(Bi * 384 + ch0)) * (size_t)NPIX;
    for (int q = t; q < 3136; q += 256) {         // 4 planes x 784 quads
        int c = q / 784, rem = q - c * 784;
        int h = rem / 14, qw = rem - h * 14;
        const float* tr = &tmp[c][h][0];
        int4   i4 = wi4[qw];
        float4 f4 = wf4[qw];
        vf4 o4;
        {
            float t0 = tr[i4.x]; o4[0] = t0 + f4.x * (tr[i4.x + 1] - t0);
            float t1 = tr[i4.y]; o4[1] = t1 + f4.y * (tr[i4.y + 1] - t1);
            float t2 = tr[i4.z]; o4[2] = t2 + f4.z * (tr[i4.z + 1] - t2);
            float t3 = tr[i4.w]; o4[3] = t3 + f4.w * (tr[i4.w + 1] - t3);
        }
        *reinterpret_cast<vf4*>(out + obase + (size_t)q * 4) = o4;
    }
}

// ---------------------------------------------------------------------------
extern "C" void kernel_launch(void* const* d_in, const int* in_sizes, int n_in,
                              void* d_out, int out_size, void* d_ws, size_t ws_size,
                              hipStream_t stream) {
    const float* x      = (const float*)d_in[0];
    const float* proj_w = (const float*)d_in[1];
    const float* proj_b = (const float*)d_in[2];
    const float* alpha  = (const float*)d_in[3];
    const float* beta   = (const float*)d_in[4];
    const float* w2     = (const float*)d_in[5];
    const float* b2     = (const float*)d_in[6];
    float* out = (float*)d_out;
    float* ws  = (float*)d_ws;

    unsigned short* Whi1  = (unsigned short*)(ws);                   // 737,280 u16
    unsigned short* Wlo1  = (unsigned short*)(ws + (size_t)368640);
    unsigned short* Xhi   = (unsigned short*)(ws + (size_t)737280);  // 344,064 u16
    unsigned short* Xlo   = (unsigned short*)(ws + (size_t)909312);
    unsigned short* Whi2  = (unsigned short*)(ws + (size_t)1081344); // 147,456 u16
    unsigned short* Wlo2  = (unsigned short*)(ws + (size_t)1155072);
    unsigned short* osThi = (unsigned short*)(ws + (size_t)1228800); // 393,216 u16
    unsigned short* osTlo = (unsigned short*)(ws + (size_t)1425408);
    // total ws ~6.5 MB

    k_front<<<dim3(9600), 256, 0, stream>>>(x, proj_w, w2, Xhi, Xlo, Whi1, Wlo1, Whi2, Wlo2);
    k_fuse <<<dim3(128),  512, 0, stream>>>(Whi1, Wlo1, Xhi, Xlo, proj_b, alpha, beta, osThi, osTlo);
    k_tail <<<dim3(1536), 256, 0, stream>>>(Whi2, Wlo2, osThi, osTlo, b2, out);
}